// Round 12
// baseline (308.438 us; speedup 1.0000x reference)
//
#include <hip/hip_runtime.h>

typedef unsigned long long u64;

#define B_ 64
#define C_ 32
#define V_ 4096
#define NELEM_ (B_*C_*16*16)   // 524288

// ---------------------------------------------------------------- utilities

__device__ __forceinline__ float keys_cubic(float x) {
  if (x >= 2.f) return 0.f;
  if (x >= 1.f) return ((-0.5f*x + 2.5f)*x - 4.f)*x + 2.f;
  return (1.5f*x - 2.5f)*x*x + 1.f;
}

__device__ __forceinline__ u64 pack_key(float d, int idx) {
  unsigned bu = __float_as_uint(d);
  unsigned m = bu ^ ((bu >> 31) ? 0xFFFFFFFFu : 0x80000000u);  // order-preserving
  return ((u64)m << 32) | (unsigned)idx;
}

// ------------------------------------------------- setup: e_sq + pool0

__global__ void setup_kernel(const float* __restrict__ f, const float* __restrict__ emb,
                             float* __restrict__ e_sq, float* __restrict__ z0) {
  int i = blockIdx.x*blockDim.x + threadIdx.x;
  if (i < V_) {
    const float4* p = (const float4*)(emb + (size_t)i*32);
    float s = 0.f;
#pragma unroll
    for (int j = 0; j < 8; ++j) { float4 q = p[j]; s += q.x*q.x + q.y*q.y + q.z*q.z + q.w*q.w; }
    e_sq[i] = s;
  }
  if (i < B_*C_) {   // z0[b][c] = mean over 16x16; z0 layout == [pos][c] for pn=1
    const float4* p = (const float4*)(f + (size_t)i*256);
    float s = 0.f;
    for (int j = 0; j < 64; ++j) { float4 q = p[j]; s += (q.x + q.y) + (q.z + q.w); }
    z0[i] = s * (1.f/256.f);
  }
}

// ---------------------------------------------------------------- argmin (scalar path)
// VERBATIM round-7 template source (passed correctness at P=1,2,4). Codes via
// wave-uniform pointers -> s_load; z in VGPRs. P=2 keeps zb at 64 regs: no spill.

template<int P>
__global__ void __launch_bounds__(256, 1) argmin_kernel(
    const float* __restrict__ z, const float* __restrict__ emb,
    const float* __restrict__ e_sq, u64* __restrict__ part_lo,
    u64* __restrict__ part_hi, int split, int N, int cpc) {
  const int tid = threadIdx.x;
  const int n0 = blockIdx.x*(256*P) + tid;
  float zb[P][32]; float zz[P];
#pragma unroll
  for (int p = 0; p < P; ++p) {
    const float4* zp = (const float4*)(z + (size_t)(n0 + p*256)*32);
#pragma unroll
    for (int i = 0; i < 8; ++i) {
      float4 q = zp[i];
      zb[p][4*i+0]=q.x; zb[p][4*i+1]=q.y; zb[p][4*i+2]=q.z; zb[p][4*i+3]=q.w;
    }
    float s = 0.f;
#pragma unroll
    for (int i = 0; i < 32; ++i) s = fmaf(zb[p][i], zb[p][i], s);
    zz[p] = s;
  }
  const int v0 = blockIdx.y * cpc;
  float bd[P]; int bi[P];
#pragma unroll
  for (int p = 0; p < P; ++p) { bd[p] = 3.4e38f; bi[p] = v0; }

  float4 qa[8], qb[8];
  {
    const float4* e4 = (const float4*)(emb + (size_t)v0*32);
#pragma unroll
    for (int i = 0; i < 8; ++i) qa[i] = e4[i];
  }
  for (int c = 0; c < cpc; c += 2) {
    const int v = v0 + c;
    {
      const float4* en = (const float4*)(emb + (size_t)(v+1)*32);
#pragma unroll
      for (int i = 0; i < 8; ++i) qb[i] = en[i];
    }
    float ev = e_sq[v];
#pragma unroll
    for (int p = 0; p < P; ++p) {
      float a0=0.f,a1=0.f,a2=0.f,a3=0.f;
#pragma unroll
      for (int i = 0; i < 8; ++i) {
        a0 = fmaf(zb[p][4*i+0], qa[i].x, a0);
        a1 = fmaf(zb[p][4*i+1], qa[i].y, a1);
        a2 = fmaf(zb[p][4*i+2], qa[i].z, a2);
        a3 = fmaf(zb[p][4*i+3], qa[i].w, a3);
      }
      float dot = (a0+a1)+(a2+a3);
      float d = (zz[p] + ev) - 2.f*dot;
      bool lt = d < bd[p];
      bd[p] = lt ? d : bd[p];
      bi[p] = lt ? v : bi[p];
    }
    int v2 = v + 2; if (v2 > V_-1) v2 = V_-1;   // prefetch clamp (last iter only)
    {
      const float4* en = (const float4*)(emb + (size_t)v2*32);
#pragma unroll
      for (int i = 0; i < 8; ++i) qa[i] = en[i];
    }
    ev = e_sq[v+1];
#pragma unroll
    for (int p = 0; p < P; ++p) {
      float a0=0.f,a1=0.f,a2=0.f,a3=0.f;
#pragma unroll
      for (int i = 0; i < 8; ++i) {
        a0 = fmaf(zb[p][4*i+0], qb[i].x, a0);
        a1 = fmaf(zb[p][4*i+1], qb[i].y, a1);
        a2 = fmaf(zb[p][4*i+2], qb[i].z, a2);
        a3 = fmaf(zb[p][4*i+3], qb[i].w, a3);
      }
      float dot = (a0+a1)+(a2+a3);
      float d = (zz[p] + ev) - 2.f*dot;
      bool lt = d < bd[p];
      bd[p] = lt ? d : bd[p];
      bi[p] = lt ? (v+1) : bi[p];
    }
  }
  u64* pp = (blockIdx.y < split) ? (part_lo + (size_t)blockIdx.y*N)
                                 : (part_hi + (size_t)(blockIdx.y - split)*N);
#pragma unroll
  for (int p = 0; p < P; ++p) pp[n0 + p*256] = pack_key(bd[p], bi[p]);
}

// ---------------------------------------------------------------- argmin (LDS path, small scales)

template<int P, int TILE>
__global__ void __launch_bounds__(256, 2) argmin2_kernel(
    const float* __restrict__ z, const float* __restrict__ emb,
    const float* __restrict__ e_sq, u64* __restrict__ part_lo,
    u64* __restrict__ part_hi, int split, int N, int cpc) {
  __shared__ float cl[TILE*32];
  __shared__ float es[TILE];
  const int tid = threadIdx.x;
  const int n0 = blockIdx.x*(256*P) + tid;
  float zb[P][32]; float zz[P];
#pragma unroll
  for (int p = 0; p < P; ++p) {
    const float4* zp = (const float4*)(z + (size_t)(n0 + p*256)*32);
#pragma unroll
    for (int i = 0; i < 8; ++i) {
      float4 q = zp[i];
      zb[p][4*i+0]=q.x; zb[p][4*i+1]=q.y; zb[p][4*i+2]=q.z; zb[p][4*i+3]=q.w;
    }
    float s = 0.f;
#pragma unroll
    for (int i = 0; i < 32; ++i) s = fmaf(zb[p][i], zb[p][i], s);
    zz[p] = s;
  }
  const int v0 = blockIdx.y * cpc;
  float bd[P]; int bi[P];
#pragma unroll
  for (int p = 0; p < P; ++p) { bd[p] = 3.4e38f; bi[p] = v0; }
  for (int t0 = 0; t0 < cpc; t0 += TILE) {
    __syncthreads();
    const float4* src = (const float4*)(emb + (size_t)(v0 + t0)*32);
    for (int e = tid; e < TILE*8; e += 256) ((float4*)cl)[e] = src[e];
    if (tid < TILE) es[tid] = e_sq[v0 + t0 + tid];
    __syncthreads();
#pragma unroll 2
    for (int c = 0; c < TILE; ++c) {
      const float4* cp = (const float4*)(cl + c*32);
      float4 q[8];
#pragma unroll
      for (int i = 0; i < 8; ++i) q[i] = cp[i];
      float ev = es[c];
#pragma unroll
      for (int p = 0; p < P; ++p) {
        float a0=0.f, a1=0.f, a2=0.f, a3=0.f;
#pragma unroll
        for (int i = 0; i < 8; ++i) {
          a0 = fmaf(zb[p][4*i+0], q[i].x, a0);
          a1 = fmaf(zb[p][4*i+1], q[i].y, a1);
          a2 = fmaf(zb[p][4*i+2], q[i].z, a2);
          a3 = fmaf(zb[p][4*i+3], q[i].w, a3);
        }
        float dot = (a0+a1)+(a2+a3);
        float d = (zz[p] + ev) - 2.f*dot;
        bool lt = d < bd[p];
        bd[p] = lt ? d : bd[p];
        bi[p] = lt ? (v0 + t0 + c) : bi[p];
      }
    }
  }
  u64* pp = (blockIdx.y < split) ? (part_lo + (size_t)blockIdx.y*N)
                                 : (part_hi + (size_t)(blockIdx.y - split)*N);
#pragma unroll
  for (int p = 0; p < P; ++p) pp[n0 + p*256] = pack_key(bd[p], bi[p]);
}

// si=0: N=64 positions. 16 blocks x 256-code chunk; wave w scans 64 codes.
__global__ void __launch_bounds__(256) argmin0_kernel(
    const float* __restrict__ z, const float* __restrict__ emb,
    const float* __restrict__ e_sq, u64* __restrict__ part_lo) {
  __shared__ u64 wkey[4][64];
  const int tid = threadIdx.x, lane = tid & 63;
  const int w = tid >> 6;
  float zb[32];
  {
    const float4* zp = (const float4*)(z + (size_t)lane*32);
#pragma unroll
    for (int i = 0; i < 8; ++i) {
      float4 q = zp[i];
      zb[4*i+0]=q.x; zb[4*i+1]=q.y; zb[4*i+2]=q.z; zb[4*i+3]=q.w;
    }
  }
  float zz = 0.f;
#pragma unroll
  for (int i = 0; i < 32; ++i) zz = fmaf(zb[i], zb[i], zz);
  const int v0 = blockIdx.x*256 + w*64;
  float bd = 3.4e38f; int bi = v0;
  for (int c = 0; c < 64; ++c) {
    const int v = v0 + c;
    const float4* e4 = (const float4*)(emb + (size_t)v*32);
    float4 q[8];
#pragma unroll
    for (int i = 0; i < 8; ++i) q[i] = e4[i];
    float a0=0.f,a1=0.f,a2=0.f,a3=0.f;
#pragma unroll
    for (int i = 0; i < 8; ++i) {
      a0 = fmaf(zb[4*i+0], q[i].x, a0);
      a1 = fmaf(zb[4*i+1], q[i].y, a1);
      a2 = fmaf(zb[4*i+2], q[i].z, a2);
      a3 = fmaf(zb[4*i+3], q[i].w, a3);
    }
    float d = (zz + e_sq[v]) - 2.f*((a0+a1)+(a2+a3));
    if (d < bd) { bd = d; bi = v; }
  }
  wkey[w][lane] = pack_key(bd, bi);
  __syncthreads();
  if (tid < 64) {
    u64 best = wkey[0][tid];
#pragma unroll
    for (int ww = 1; ww < 4; ++ww) { u64 kk = wkey[ww][tid]; if (kk < best) best = kk; }
    part_lo[blockIdx.x*64 + tid] = best;
  }
}

// ---------------------------------------------------------------- fused upconv

template<int PN, int NEXT_PN, bool FIRST>
__global__ void __launch_bounds__(512) upconv_kernel(
    const u64* __restrict__ part_lo, const u64* __restrict__ part_hi,
    int split, int nvc,
    const float* __restrict__ emb,
    const float* __restrict__ phi_w,   // [32][32][3][3] (offset by phi idx)
    const float* __restrict__ phi_b,   // [32]
    const float* __restrict__ f,
    float* __restrict__ f_hat,
    float* __restrict__ f_rest,
    float* __restrict__ z_next,
    float* __restrict__ loss_part)
{
  constexpr int PN2 = PN*PN;
  constexpr int NPOS = B_*PN2;
  constexpr int S = 512/PN2 < 1 ? 1 : 512/PN2;   // reduce slices per position
  constexpr bool POOLED = (NEXT_PN != 0 && NEXT_PN < 16);
  const int b = blockIdx.x;
  const int cg = blockIdx.y;
  const int tid = threadIdx.x;

  __shared__ u64   red[512];
  __shared__ int   idx_s[PN2];
  __shared__ float W4[16][4];
  __shared__ int   I0[16];
  __shared__ float tmp_s[(PN < 16) ? C_*PN*16 : 1];
  __shared__ float pool_s[POOLED ? 8*256 : 1];
  union HupHs { float hup[C_*16*18]; float hs[C_*16*18]; };  // hup row: [16 + 2 pad]
  __shared__ HupHs u;
  __shared__ float wsum[8];

  // ---- stage 0: parallel reduce of chunk partials (deterministic min on keys)
  {
    const int p = tid % PN2;
    const int s = tid / PN2;
    const int n = b*PN2 + p;
    u64 best = ~0ull;
    for (int vc = s; vc < nvc; vc += S) {
      const u64* pp = (vc < split) ? (part_lo + (size_t)vc*NPOS)
                                   : (part_hi + (size_t)(vc - split)*NPOS);
      u64 kk = pp[n];
      if (kk < best) best = kk;
    }
    red[tid] = best;
    __syncthreads();
#pragma unroll
    for (int h = S/2; h > 0; h >>= 1) {
      if (tid < h*PN2) {
        u64 o = red[tid + h*PN2];
        if (o < red[tid]) red[tid] = o;
      }
      __syncthreads();
    }
    if (tid < PN2) idx_s[tid] = (int)(red[tid] & 0xFFFFFFFFull);
  }

  if (PN < 16 && tid < 16) {
    float sf = (tid + 0.5f) * ((float)PN/16.f) - 0.5f;
    int i0 = (int)floorf(sf) - 1;
    float w[4]; float tot = 0.f;
#pragma unroll
    for (int t = 0; t < 4; ++t) {
      int i = i0 + t;
      float wv = (i >= 0 && i < PN) ? keys_cubic(fabsf(sf - (float)i)) : 0.f;
      w[t] = wv; tot += wv;
    }
    float r = 1.f/tot;
#pragma unroll
    for (int t = 0; t < 4; ++t) W4[tid][t] = w[t]*r;
    I0[tid] = i0;
  }
  __syncthreads();

  // ---- gather codes
  if (PN < 16) {
    for (int e = tid; e < C_*PN2; e += 512) {
      int c = e / PN2, p = e % PN2;
      u.hs[c*PN2 + p] = emb[(size_t)idx_s[p]*32 + c];
    }
  } else {
    for (int e = tid; e < C_*256; e += 512) {
      int c = e >> 8, p = e & 255;
      int y = p >> 4, x = p & 15;
      u.hup[(c*16 + y)*18 + 1 + x] = emb[(size_t)idx_s[p]*32 + c];
    }
    for (int e = tid; e < C_*16; e += 512) { u.hup[e*18] = 0.f; u.hup[e*18 + 17] = 0.f; }
  }
  __syncthreads();

  // ---- separable bicubic upsample PN -> 16
  if (PN < 16) {
    for (int e = tid; e < C_*PN*16; e += 512) {       // x pass
      int jx = e & 15; int rest = e >> 4;
      int iy = rest % PN; int c = rest / PN;
      int i0 = I0[jx];
      float s = 0.f;
#pragma unroll
      for (int t = 0; t < 4; ++t) {
        int ix = i0 + t; int ixc = min(max(ix, 0), PN-1);
        s += W4[jx][t] * u.hs[(c*PN + iy)*PN + ixc];
      }
      tmp_s[(c*PN + iy)*16 + jx] = s;
    }
    __syncthreads();
    for (int e = tid; e < C_*16; e += 512) { u.hup[e*18] = 0.f; u.hup[e*18 + 17] = 0.f; }
    for (int e = tid; e < C_*256; e += 512) {          // y pass
      int jx = e & 15; int jy = (e >> 4) & 15; int c = e >> 8;
      int i0 = I0[jy];
      float s = 0.f;
#pragma unroll
      for (int t = 0; t < 4; ++t) {
        int iy = i0 + t; int iyc = min(max(iy, 0), PN-1);
        s += W4[jy][t] * tmp_s[(c*PN + iyc)*16 + jx];
      }
      u.hup[(c*16 + jy)*18 + 1 + jx] = s;
    }
    __syncthreads();
  }

  // ---- conv3x3 (zero pad) + blend: thread = (px, co-subgroup of 4)
  const int px = tid & 255;
  const int g  = tid >> 8;               // 0,1
  const int y  = px >> 4, x = px & 15;
  const int co0 = cg*8 + g*4;
  const float* wbase = phi_w + (size_t)co0*32*9;   // wave-uniform -> scalar loads
  float acc[4];
#pragma unroll
  for (int o = 0; o < 4; ++o) acc[o] = phi_b[co0 + o];
  for (int ci = 0; ci < 32; ++ci) {
    float wn[9];
#pragma unroll
    for (int ky = 0; ky < 3; ++ky) {
      int yy = y + ky - 1;
      bool v = (yy >= 0 && yy <= 15);
      const float* r = &u.hup[(ci*16 + (v ? yy : 0))*18 + x];
      wn[ky*3+0] = v ? r[0] : 0.f;
      wn[ky*3+1] = v ? r[1] : 0.f;
      wn[ky*3+2] = v ? r[2] : 0.f;
    }
#pragma unroll
    for (int o = 0; o < 4; ++o) {
      const float* wp = wbase + ((size_t)o*32 + ci)*9;
#pragma unroll
      for (int t = 0; t < 9; ++t) acc[o] = fmaf(wp[t], wn[t], acc[o]);
    }
  }

  // ---- updates + next-scale pooled z + loss
  float lsum = 0.f;
#pragma unroll
  for (int o = 0; o < 4; ++o) {
    int co = co0 + o;
    float hv = 0.5f*u.hup[(co*16 + y)*18 + 1 + x] + 0.5f*acc[o];
    size_t gi = (((size_t)b*C_ + co)*16 + y)*16 + x;
    float fv = f[gi];
    float fh = FIRST ? hv : (f_hat[gi] + hv);
    f_hat[gi] = fh;
    if constexpr (NEXT_PN != 0) {
      float nfr = FIRST ? (fv - hv) : (f_rest[gi] - hv);
      if constexpr (NEXT_PN == 16) {
        z_next[((size_t)b*256 + px)*32 + co] = nfr;   // f_rest dead after this scale
      } else {
        f_rest[gi] = nfr;
        pool_s[(g*4 + o)*256 + px] = nfr;
      }
    }
    float dd = fh - fv;
    lsum = fmaf(dd, dd, lsum);
  }
  if constexpr (POOLED) {
    constexpr int NP = (NEXT_PN > 0) ? NEXT_PN : 1;
    constexpr int NP2 = NP*NP;
    constexpr int KP = 16/NP;
    __syncthreads();
    if (tid < 8*NP2) {
      int c_l = tid / NP2, p = tid % NP2;
      int yy = (p / NP)*KP, xx = (p % NP)*KP;
      float s = 0.f;
      for (int a = 0; a < KP; ++a)
        for (int e = 0; e < KP; ++e)
          s += pool_s[c_l*256 + (yy + a)*16 + xx + e];
      z_next[((size_t)b*NP2 + p)*32 + cg*8 + c_l] = s * (1.f/(float)(KP*KP));
    }
  }
  // deterministic block loss reduction (8 waves)
#pragma unroll
  for (int off = 32; off > 0; off >>= 1) lsum += __shfl_down(lsum, off);
  if ((tid & 63) == 0) wsum[tid >> 6] = lsum;
  __syncthreads();
  if (tid == 0) {
    float s = 0.f;
#pragma unroll
    for (int i = 0; i < 8; ++i) s += wsum[i];
    loss_part[blockIdx.y*64 + blockIdx.x] = s;
  }
}

__global__ void loss_kernel(const float* __restrict__ loss_part, float* __restrict__ out_loss) {
  __shared__ float s[256];
  int t = threadIdx.x;
  float v = 0.f;
#pragma unroll
  for (int i = 0; i < 5; ++i) v += loss_part[i*256 + t];
  s[t] = v;
  __syncthreads();
  for (int off = 128; off > 0; off >>= 1) {
    if (t < off) s[t] += s[t + off];
    __syncthreads();
  }
  if (t == 0) out_loss[0] = s[0] * (1.25f / (5.f * (float)NELEM_));
}

// ---------------------------------------------------------------- launch

extern "C" void kernel_launch(void* const* d_in, const int* in_sizes, int n_in,
                              void* d_out, int out_size, void* d_ws, size_t ws_size,
                              hipStream_t stream) {
  const float* f     = (const float*)d_in[0];
  const float* emb   = (const float*)d_in[1];
  const float* phi_w = (const float*)d_in[2];   // [4][32][32][3][3]
  const float* phi_b = (const float*)d_in[3];   // [4][32]
  float* f_hat    = (float*)d_out;              // [524288]
  float* out_loss = f_hat + NELEM_;             // [1]

  char* ws = (char*)d_ws;
  float* f_rest  = (float*)ws;                         // 2 MB
  float* z       = f_rest + NELEM_;                    // 2 MB
  u64*   part_lo = (u64*)(z + NELEM_);                 // 2 MB (262144 keys)
  float* e_sq    = (float*)(part_lo + 262144);         // 16 KB
  float* loss_part = e_sq + V_;                        // 5*256 floats
  u64*   part_hi = (u64*)f_rest;                       // alias (unused by scalar configs)

  // PHI_IDX from exact float64 replay of np.linspace + np.argmin: [0,1,2,2,3]
  const float* pw0 = phi_w;                 const float* pb0 = phi_b;
  const float* pw1 = phi_w + 1*32*32*9;     const float* pb1 = phi_b + 1*32;
  const float* pw2 = phi_w + 2*32*32*9;     const float* pb2 = phi_b + 2*32;
  const float* pw3 = phi_w + 3*32*32*9;     const float* pb3 = phi_b + 3*32;

  setup_kernel<<<16, 256, 0, stream>>>(f, emb, e_sq, z);

  dim3 cgrid(B_, 4);
  // si=0 (pn=1): N=64, 16 chunks of 256 codes
  argmin0_kernel<<<16, 256, 0, stream>>>(z, emb, e_sq, part_lo);
  upconv_kernel<1, 2, true><<<cgrid, 512, 0, stream>>>(part_lo, part_hi, 64, 16,
      emb, pw0, pb0, f, f_hat, f_rest, z, loss_part + 0*256);
  // si=1 (pn=2): N=256, P=1, 128 chunks x 32 codes (LDS path)
  argmin2_kernel<1,32><<<dim3(1,128), 256, 0, stream>>>(z, emb, e_sq, part_lo, part_hi, 192, 256, 32);
  upconv_kernel<2, 4, false><<<cgrid, 512, 0, stream>>>(part_lo, part_hi, 192, 128,
      emb, pw1, pb1, f, f_hat, f_rest, z, loss_part + 1*256);
  // si=2 (pn=4): N=1024, P=2, 128 chunks x 32 codes (LDS path)
  argmin2_kernel<2,32><<<dim3(2,128), 256, 0, stream>>>(z, emb, e_sq, part_lo, part_hi, 192, 1024, 32);
  upconv_kernel<4, 8, false><<<cgrid, 512, 0, stream>>>(part_lo, part_hi, 192, 128,
      emb, pw2, pb2, f, f_hat, f_rest, z, loss_part + 2*256);
  // si=3 (pn=8): N=4096, scalar P=2, 8 pos-blocks x 32 chunks x 128 codes (1 MB partials)
  argmin_kernel<2><<<dim3(8,32), 256, 0, stream>>>(z, emb, e_sq, part_lo, part_hi, 32, 4096, 128);
  upconv_kernel<8, 16, false><<<cgrid, 512, 0, stream>>>(part_lo, part_hi, 32, 32,
      emb, pw2, pb2, f, f_hat, f_rest, z, loss_part + 3*256);
  // si=4 (pn=16): N=16384, scalar P=2, 32 pos-blocks x 16 chunks x 256 codes (part_lo exactly full)
  argmin_kernel<2><<<dim3(32,16), 256, 0, stream>>>(z, emb, e_sq, part_lo, part_hi, 16, 16384, 256);
  upconv_kernel<16, 0, false><<<cgrid, 512, 0, stream>>>(part_lo, part_hi, 16, 16,
      emb, pw3, pb3, f, f_hat, f_rest, z, loss_part + 4*256);

  loss_kernel<<<1, 256, 0, stream>>>(loss_part, out_loss);
}

// Round 13
// 268.431 us; speedup vs baseline: 1.1490x; 1.1490x over previous
//
#include <hip/hip_runtime.h>

typedef unsigned long long u64;

#define B_ 64
#define C_ 32
#define V_ 4096
#define NELEM_ (B_*C_*16*16)   // 524288

// ---------------------------------------------------------------- utilities

__device__ __forceinline__ float keys_cubic(float x) {
  if (x >= 2.f) return 0.f;
  if (x >= 1.f) return ((-0.5f*x + 2.5f)*x - 4.f)*x + 2.f;
  return (1.5f*x - 2.5f)*x*x + 1.f;
}

__device__ __forceinline__ u64 pack_key(float d, int idx) {
  unsigned bu = __float_as_uint(d);
  unsigned m = bu ^ ((bu >> 31) ? 0xFFFFFFFFu : 0x80000000u);  // order-preserving
  return ((u64)m << 32) | (unsigned)idx;
}

// ------------------------------------------------- setup: e_sq + pool0

__global__ void setup_kernel(const float* __restrict__ f, const float* __restrict__ emb,
                             float* __restrict__ e_sq, float* __restrict__ z0) {
  int i = blockIdx.x*blockDim.x + threadIdx.x;
  if (i < V_) {
    const float4* p = (const float4*)(emb + (size_t)i*32);
    float s = 0.f;
#pragma unroll
    for (int j = 0; j < 8; ++j) { float4 q = p[j]; s += q.x*q.x + q.y*q.y + q.z*q.z + q.w*q.w; }
    e_sq[i] = s;
  }
  if (i < B_*C_) {   // z0[b][c] = mean over 16x16; z0 layout == [pos][c] for pn=1
    const float4* p = (const float4*)(f + (size_t)i*256);
    float s = 0.f;
    for (int j = 0; j < 64; ++j) { float4 q = p[j]; s += (q.x + q.y) + (q.z + q.w); }
    z0[i] = s * (1.f/256.f);
  }
}

// ---------------------------------------------------------------- argmin (LDS path)
// Proven kernel (rounds 3/5/8/11): codes staged in LDS tiles, z in registers,
// per-chunk partials to part2D rows (no atomics). Exact reference association:
// d = (zz + e_sq[v]) - 2*dot, dot via 4 accumulators + (a0+a1)+(a2+a3).

template<int P, int TILE>
__global__ void __launch_bounds__(256, 2) argmin2_kernel(
    const float* __restrict__ z, const float* __restrict__ emb,
    const float* __restrict__ e_sq, u64* __restrict__ part_lo,
    u64* __restrict__ part_hi, int split, int N, int cpc) {
  __shared__ float cl[TILE*32];
  __shared__ float es[TILE];
  const int tid = threadIdx.x;
  const int n0 = blockIdx.x*(256*P) + tid;
  float zb[P][32]; float zz[P];
#pragma unroll
  for (int p = 0; p < P; ++p) {
    const float4* zp = (const float4*)(z + (size_t)(n0 + p*256)*32);
#pragma unroll
    for (int i = 0; i < 8; ++i) {
      float4 q = zp[i];
      zb[p][4*i+0]=q.x; zb[p][4*i+1]=q.y; zb[p][4*i+2]=q.z; zb[p][4*i+3]=q.w;
    }
    float s = 0.f;
#pragma unroll
    for (int i = 0; i < 32; ++i) s = fmaf(zb[p][i], zb[p][i], s);
    zz[p] = s;
  }
  const int v0 = blockIdx.y * cpc;
  float bd[P]; int bi[P];
#pragma unroll
  for (int p = 0; p < P; ++p) { bd[p] = 3.4e38f; bi[p] = v0; }
  for (int t0 = 0; t0 < cpc; t0 += TILE) {
    __syncthreads();
    const float4* src = (const float4*)(emb + (size_t)(v0 + t0)*32);
    for (int e = tid; e < TILE*8; e += 256) ((float4*)cl)[e] = src[e];
    if (tid < TILE) es[tid] = e_sq[v0 + t0 + tid];
    __syncthreads();
#pragma unroll 2
    for (int c = 0; c < TILE; ++c) {
      const float4* cp = (const float4*)(cl + c*32);
      float4 q[8];
#pragma unroll
      for (int i = 0; i < 8; ++i) q[i] = cp[i];
      float ev = es[c];
#pragma unroll
      for (int p = 0; p < P; ++p) {
        float a0=0.f, a1=0.f, a2=0.f, a3=0.f;
#pragma unroll
        for (int i = 0; i < 8; ++i) {
          a0 = fmaf(zb[p][4*i+0], q[i].x, a0);
          a1 = fmaf(zb[p][4*i+1], q[i].y, a1);
          a2 = fmaf(zb[p][4*i+2], q[i].z, a2);
          a3 = fmaf(zb[p][4*i+3], q[i].w, a3);
        }
        float dot = (a0+a1)+(a2+a3);
        float d = (zz[p] + ev) - 2.f*dot;
        bool lt = d < bd[p];
        bd[p] = lt ? d : bd[p];
        bi[p] = lt ? (v0 + t0 + c) : bi[p];
      }
    }
  }
  u64* pp = (blockIdx.y < split) ? (part_lo + (size_t)blockIdx.y*N)
                                 : (part_hi + (size_t)(blockIdx.y - split)*N);
#pragma unroll
  for (int p = 0; p < P; ++p) pp[n0 + p*256] = pack_key(bd[p], bi[p]);
}

// si=0: N=64 positions. 16 blocks x 256-code chunk; wave w scans 64 codes.
__global__ void __launch_bounds__(256) argmin0_kernel(
    const float* __restrict__ z, const float* __restrict__ emb,
    const float* __restrict__ e_sq, u64* __restrict__ part_lo) {
  __shared__ u64 wkey[4][64];
  const int tid = threadIdx.x, lane = tid & 63;
  const int w = tid >> 6;
  float zb[32];
  {
    const float4* zp = (const float4*)(z + (size_t)lane*32);
#pragma unroll
    for (int i = 0; i < 8; ++i) {
      float4 q = zp[i];
      zb[4*i+0]=q.x; zb[4*i+1]=q.y; zb[4*i+2]=q.z; zb[4*i+3]=q.w;
    }
  }
  float zz = 0.f;
#pragma unroll
  for (int i = 0; i < 32; ++i) zz = fmaf(zb[i], zb[i], zz);
  const int v0 = blockIdx.x*256 + w*64;
  float bd = 3.4e38f; int bi = v0;
  for (int c = 0; c < 64; ++c) {
    const int v = v0 + c;
    const float4* e4 = (const float4*)(emb + (size_t)v*32);
    float4 q[8];
#pragma unroll
    for (int i = 0; i < 8; ++i) q[i] = e4[i];
    float a0=0.f,a1=0.f,a2=0.f,a3=0.f;
#pragma unroll
    for (int i = 0; i < 8; ++i) {
      a0 = fmaf(zb[4*i+0], q[i].x, a0);
      a1 = fmaf(zb[4*i+1], q[i].y, a1);
      a2 = fmaf(zb[4*i+2], q[i].z, a2);
      a3 = fmaf(zb[4*i+3], q[i].w, a3);
    }
    float d = (zz + e_sq[v]) - 2.f*((a0+a1)+(a2+a3));
    if (d < bd) { bd = d; bi = v; }
  }
  wkey[w][lane] = pack_key(bd, bi);
  __syncthreads();
  if (tid < 64) {
    u64 best = wkey[0][tid];
#pragma unroll
    for (int ww = 1; ww < 4; ++ww) { u64 kk = wkey[ww][tid]; if (kk < best) best = kk; }
    part_lo[blockIdx.x*64 + tid] = best;
  }
}

// ---------------------------------------------------------------- fused upconv

template<int PN, int NEXT_PN, bool FIRST>
__global__ void __launch_bounds__(512) upconv_kernel(
    const u64* __restrict__ part_lo, const u64* __restrict__ part_hi,
    int split, int nvc,
    const float* __restrict__ emb,
    const float* __restrict__ phi_w,   // [32][32][3][3] (offset by phi idx)
    const float* __restrict__ phi_b,   // [32]
    const float* __restrict__ f,
    float* __restrict__ f_hat,
    float* __restrict__ f_rest,
    float* __restrict__ z_next,
    float* __restrict__ loss_part)
{
  constexpr int PN2 = PN*PN;
  constexpr int NPOS = B_*PN2;
  constexpr int S = 512/PN2 < 1 ? 1 : 512/PN2;   // reduce slices per position
  constexpr bool POOLED = (NEXT_PN != 0 && NEXT_PN < 16);
  const int b = blockIdx.x;
  const int cg = blockIdx.y;
  const int tid = threadIdx.x;

  __shared__ u64   red[512];
  __shared__ int   idx_s[PN2];
  __shared__ float W4[16][4];
  __shared__ int   I0[16];
  __shared__ float tmp_s[(PN < 16) ? C_*PN*16 : 1];
  __shared__ float pool_s[POOLED ? 8*256 : 1];
  union HupHs { float hup[C_*16*18]; float hs[C_*16*18]; };  // hup row: [16 + 2 pad]
  __shared__ HupHs u;
  __shared__ float wsum[8];

  // ---- stage 0: parallel reduce of chunk partials (deterministic min on keys)
  {
    const int p = tid % PN2;
    const int s = tid / PN2;
    const int n = b*PN2 + p;
    u64 best = ~0ull;
    for (int vc = s; vc < nvc; vc += S) {
      const u64* pp = (vc < split) ? (part_lo + (size_t)vc*NPOS)
                                   : (part_hi + (size_t)(vc - split)*NPOS);
      u64 kk = pp[n];
      if (kk < best) best = kk;
    }
    red[tid] = best;
    __syncthreads();
#pragma unroll
    for (int h = S/2; h > 0; h >>= 1) {
      if (tid < h*PN2) {
        u64 o = red[tid + h*PN2];
        if (o < red[tid]) red[tid] = o;
      }
      __syncthreads();
    }
    if (tid < PN2) idx_s[tid] = (int)(red[tid] & 0xFFFFFFFFull);
  }

  if (PN < 16 && tid < 16) {
    float sf = (tid + 0.5f) * ((float)PN/16.f) - 0.5f;
    int i0 = (int)floorf(sf) - 1;
    float w[4]; float tot = 0.f;
#pragma unroll
    for (int t = 0; t < 4; ++t) {
      int i = i0 + t;
      float wv = (i >= 0 && i < PN) ? keys_cubic(fabsf(sf - (float)i)) : 0.f;
      w[t] = wv; tot += wv;
    }
    float r = 1.f/tot;
#pragma unroll
    for (int t = 0; t < 4; ++t) W4[tid][t] = w[t]*r;
    I0[tid] = i0;
  }
  __syncthreads();

  // ---- gather codes
  if (PN < 16) {
    for (int e = tid; e < C_*PN2; e += 512) {
      int c = e / PN2, p = e % PN2;
      u.hs[c*PN2 + p] = emb[(size_t)idx_s[p]*32 + c];
    }
  } else {
    for (int e = tid; e < C_*256; e += 512) {
      int c = e >> 8, p = e & 255;
      int y = p >> 4, x = p & 15;
      u.hup[(c*16 + y)*18 + 1 + x] = emb[(size_t)idx_s[p]*32 + c];
    }
    for (int e = tid; e < C_*16; e += 512) { u.hup[e*18] = 0.f; u.hup[e*18 + 17] = 0.f; }
  }
  __syncthreads();

  // ---- separable bicubic upsample PN -> 16
  if (PN < 16) {
    for (int e = tid; e < C_*PN*16; e += 512) {       // x pass
      int jx = e & 15; int rest = e >> 4;
      int iy = rest % PN; int c = rest / PN;
      int i0 = I0[jx];
      float s = 0.f;
#pragma unroll
      for (int t = 0; t < 4; ++t) {
        int ix = i0 + t; int ixc = min(max(ix, 0), PN-1);
        s += W4[jx][t] * u.hs[(c*PN + iy)*PN + ixc];
      }
      tmp_s[(c*PN + iy)*16 + jx] = s;
    }
    __syncthreads();
    for (int e = tid; e < C_*16; e += 512) { u.hup[e*18] = 0.f; u.hup[e*18 + 17] = 0.f; }
    for (int e = tid; e < C_*256; e += 512) {          // y pass
      int jx = e & 15; int jy = (e >> 4) & 15; int c = e >> 8;
      int i0 = I0[jy];
      float s = 0.f;
#pragma unroll
      for (int t = 0; t < 4; ++t) {
        int iy = i0 + t; int iyc = min(max(iy, 0), PN-1);
        s += W4[jy][t] * tmp_s[(c*PN + iyc)*16 + jx];
      }
      u.hup[(c*16 + jy)*18 + 1 + jx] = s;
    }
    __syncthreads();
  }

  // ---- conv3x3 (zero pad) + blend: thread = (px, co-subgroup of 4)
  const int px = tid & 255;
  const int g  = tid >> 8;               // 0,1
  const int y  = px >> 4, x = px & 15;
  const int co0 = cg*8 + g*4;
  const float* wbase = phi_w + (size_t)co0*32*9;   // wave-uniform -> scalar loads
  float acc[4];
#pragma unroll
  for (int o = 0; o < 4; ++o) acc[o] = phi_b[co0 + o];
  for (int ci = 0; ci < 32; ++ci) {
    float wn[9];
#pragma unroll
    for (int ky = 0; ky < 3; ++ky) {
      int yy = y + ky - 1;
      bool v = (yy >= 0 && yy <= 15);
      const float* r = &u.hup[(ci*16 + (v ? yy : 0))*18 + x];
      wn[ky*3+0] = v ? r[0] : 0.f;
      wn[ky*3+1] = v ? r[1] : 0.f;
      wn[ky*3+2] = v ? r[2] : 0.f;
    }
#pragma unroll
    for (int o = 0; o < 4; ++o) {
      const float* wp = wbase + ((size_t)o*32 + ci)*9;
#pragma unroll
      for (int t = 0; t < 9; ++t) acc[o] = fmaf(wp[t], wn[t], acc[o]);
    }
  }

  // ---- updates + next-scale pooled z + loss
  float lsum = 0.f;
#pragma unroll
  for (int o = 0; o < 4; ++o) {
    int co = co0 + o;
    float hv = 0.5f*u.hup[(co*16 + y)*18 + 1 + x] + 0.5f*acc[o];
    size_t gi = (((size_t)b*C_ + co)*16 + y)*16 + x;
    float fv = f[gi];
    float fh = FIRST ? hv : (f_hat[gi] + hv);
    f_hat[gi] = fh;
    if constexpr (NEXT_PN != 0) {
      float nfr = FIRST ? (fv - hv) : (f_rest[gi] - hv);
      if constexpr (NEXT_PN == 16) {
        z_next[((size_t)b*256 + px)*32 + co] = nfr;   // f_rest dead after this scale
      } else {
        f_rest[gi] = nfr;
        pool_s[(g*4 + o)*256 + px] = nfr;
      }
    }
    float dd = fh - fv;
    lsum = fmaf(dd, dd, lsum);
  }
  if constexpr (POOLED) {
    constexpr int NP = (NEXT_PN > 0) ? NEXT_PN : 1;
    constexpr int NP2 = NP*NP;
    constexpr int KP = 16/NP;
    __syncthreads();
    if (tid < 8*NP2) {
      int c_l = tid / NP2, p = tid % NP2;
      int yy = (p / NP)*KP, xx = (p % NP)*KP;
      float s = 0.f;
      for (int a = 0; a < KP; ++a)
        for (int e = 0; e < KP; ++e)
          s += pool_s[c_l*256 + (yy + a)*16 + xx + e];
      z_next[((size_t)b*NP2 + p)*32 + cg*8 + c_l] = s * (1.f/(float)(KP*KP));
    }
  }
  // deterministic block loss reduction (8 waves)
#pragma unroll
  for (int off = 32; off > 0; off >>= 1) lsum += __shfl_down(lsum, off);
  if ((tid & 63) == 0) wsum[tid >> 6] = lsum;
  __syncthreads();
  if (tid == 0) {
    float s = 0.f;
#pragma unroll
    for (int i = 0; i < 8; ++i) s += wsum[i];
    loss_part[blockIdx.y*64 + blockIdx.x] = s;
  }
}

__global__ void loss_kernel(const float* __restrict__ loss_part, float* __restrict__ out_loss) {
  __shared__ float s[256];
  int t = threadIdx.x;
  float v = 0.f;
#pragma unroll
  for (int i = 0; i < 5; ++i) v += loss_part[i*256 + t];
  s[t] = v;
  __syncthreads();
  for (int off = 128; off > 0; off >>= 1) {
    if (t < off) s[t] += s[t + off];
    __syncthreads();
  }
  if (t == 0) out_loss[0] = s[0] * (1.25f / (5.f * (float)NELEM_));
}

// ---------------------------------------------------------------- launch

extern "C" void kernel_launch(void* const* d_in, const int* in_sizes, int n_in,
                              void* d_out, int out_size, void* d_ws, size_t ws_size,
                              hipStream_t stream) {
  const float* f     = (const float*)d_in[0];
  const float* emb   = (const float*)d_in[1];
  const float* phi_w = (const float*)d_in[2];   // [4][32][32][3][3]
  const float* phi_b = (const float*)d_in[3];   // [4][32]
  float* f_hat    = (float*)d_out;              // [524288]
  float* out_loss = f_hat + NELEM_;             // [1]

  char* ws = (char*)d_ws;
  float* f_rest  = (float*)ws;                         // 2 MB; aliased as part_hi for si=4
  float* z       = f_rest + NELEM_;                    // 2 MB
  u64*   part_lo = (u64*)(z + NELEM_);                 // 2 MB (262144 keys)
  float* e_sq    = (float*)(part_lo + 262144);         // 16 KB
  float* loss_part = e_sq + V_;                        // 5*256 floats
  u64*   part_hi = (u64*)f_rest;

  // PHI_IDX from exact float64 replay of np.linspace + np.argmin: [0,1,2,2,3]
  const float* pw0 = phi_w;                 const float* pb0 = phi_b;
  const float* pw1 = phi_w + 1*32*32*9;     const float* pb1 = phi_b + 1*32;
  const float* pw2 = phi_w + 2*32*32*9;     const float* pb2 = phi_b + 2*32;
  const float* pw3 = phi_w + 3*32*32*9;     const float* pb3 = phi_b + 3*32;

  setup_kernel<<<16, 256, 0, stream>>>(f, emb, e_sq, z);

  dim3 cgrid(B_, 4);
  // si=0 (pn=1): N=64, 16 chunks of 256 codes
  argmin0_kernel<<<16, 256, 0, stream>>>(z, emb, e_sq, part_lo);
  upconv_kernel<1, 2, true><<<cgrid, 512, 0, stream>>>(part_lo, part_hi, 64, 16,
      emb, pw0, pb0, f, f_hat, f_rest, z, loss_part + 0*256);
  // si=1 (pn=2): N=256, P=1, 128 chunks x 32 codes (LDS path)
  argmin2_kernel<1,32><<<dim3(1,128), 256, 0, stream>>>(z, emb, e_sq, part_lo, part_hi, 192, 256, 32);
  upconv_kernel<2, 4, false><<<cgrid, 512, 0, stream>>>(part_lo, part_hi, 192, 128,
      emb, pw1, pb1, f, f_hat, f_rest, z, loss_part + 1*256);
  // si=2 (pn=4): N=1024, P=2, 128 chunks x 32 codes (LDS path)
  argmin2_kernel<2,32><<<dim3(2,128), 256, 0, stream>>>(z, emb, e_sq, part_lo, part_hi, 192, 1024, 32);
  upconv_kernel<4, 8, false><<<cgrid, 512, 0, stream>>>(part_lo, part_hi, 192, 128,
      emb, pw2, pb2, f, f_hat, f_rest, z, loss_part + 2*256);
  // si=3 (pn=8): N=4096, P=4, 64 chunks x 64 codes (part_lo exactly full)
  argmin2_kernel<4,64><<<dim3(4,64), 256, 0, stream>>>(z, emb, e_sq, part_lo, part_hi, 96, 4096, 64);
  upconv_kernel<8, 16, false><<<cgrid, 512, 0, stream>>>(part_lo, part_hi, 96, 64,
      emb, pw2, pb2, f, f_hat, f_rest, z, loss_part + 3*256);
  // si=4 (pn=16): N=16384, P=4, 32 chunks x 128 codes; chunks 16..31 -> part_hi
  argmin2_kernel<4,64><<<dim3(16,32), 256, 0, stream>>>(z, emb, e_sq, part_lo, part_hi, 16, 16384, 128);
  upconv_kernel<16, 0, false><<<cgrid, 512, 0, stream>>>(part_lo, part_hi, 16, 32,
      emb, pw3, pb3, f, f_hat, f_rest, z, loss_part + 4*256);

  loss_kernel<<<1, 256, 0, stream>>>(loss_part, out_loss);
}